// Round 2
// baseline (849.225 us; speedup 1.0000x reference)
//
#include <hip/hip_runtime.h>
#include <math.h>

#define S_ 4096
#define B_ 16
#define H_ 16
#define D_ 1024
#define DK_ 64
#define SCALE_ 0.125f

using f4 = float4;

__device__ __forceinline__ float dot4(f4 a, f4 b){
  return a.x*b.x + a.y*b.y + a.z*b.z + a.w*b.w;
}

// ---------------- q = query @ Wq  (atomic m-split) ----------------
__global__ __launch_bounds__(256) void k_qgemm(const float* __restrict__ query,
                                               const float* __restrict__ Wq,
                                               float* __restrict__ q){
  int hd = (blockIdx.x & 3)*256 + threadIdx.x;
  int m0 = (blockIdx.x >> 2)*16;
  float acc[B_];
#pragma unroll
  for (int b=0;b<B_;b++) acc[b] = 0.f;
#pragma unroll
  for (int i=0;i<16;i++){
    float w = Wq[(size_t)(m0+i)*D_ + hd];
#pragma unroll
    for (int b=0;b<B_;b++) acc[b] += query[b*D_ + m0 + i] * w;
  }
  for (int b=0;b<B_;b++) atomicAdd(&q[b*D_ + hd], acc[b]);
}

// ---------------- qq = q + qpb ----------------
__global__ __launch_bounds__(256) void k_qq(const float* __restrict__ q,
                                            const float* __restrict__ qpb,
                                            float* __restrict__ qq){
  int i = blockIdx.x*256 + threadIdx.x;   // 16384
  qq[i] = q[i] + qpb[i & 1023];
}

// ---------------- wq_eff[b][h][m] = SCALE * sum_d Wk[m][h*64+d]*qq[b][h][d] ----------------
__global__ __launch_bounds__(256) void k_wqeff(const float* __restrict__ Wk,
                                               const float* __restrict__ qq,
                                               float* __restrict__ wq){
  int h  = blockIdx.x & 15;
  int mc = blockIdx.x >> 4;          // 0..255
  int w    = threadIdx.x >> 6;       // 4 waves -> 4 m values
  int lane = threadIdx.x & 63;
  int m = mc*4 + w;
  int bq = lane >> 4, d4 = lane & 15;
  f4 wk4 = *(const f4*)&Wk[(size_t)m*D_ + h*DK_ + d4*4];
#pragma unroll
  for (int it=0; it<4; it++){
    int b = it*4 + bq;
    f4 q4 = *(const f4*)&qq[b*D_ + h*DK_ + d4*4];
    float p = dot4(wk4, q4);
    p += __shfl_xor(p, 1);
    p += __shfl_xor(p, 2);
    p += __shfl_xor(p, 4);
    p += __shfl_xor(p, 8);
    if (d4 == 0) wq[(size_t)b*H_*D_ + h*D_ + m] = p * SCALE_;
  }
}

// ---------------- bd[b][h][j] = SCALE * (q[b,h,:].kpe[j,h,:] + kpb[j,h]) ----------------
__global__ __launch_bounds__(256) void k_bd(const float* __restrict__ q,
                                            const float* __restrict__ kpe,
                                            const float* __restrict__ kpb,
                                            float* __restrict__ bd){
  int b = blockIdx.x >> 4, h = blockIdx.x & 15;
  __shared__ float kl[128*76];
  f4 qv[16];
#pragma unroll
  for (int d4=0; d4<16; d4++) qv[d4] = *(const f4*)&q[b*D_ + h*DK_ + d4*4];
  int t = threadIdx.x;
  for (int tile=0; tile<32; tile++){
    int j0 = tile*128;
    __syncthreads();
    for (int it=0; it<8; it++){
      int idx = it*256 + t;
      int jl = idx >> 4, d4 = idx & 15;
      *(f4*)&kl[jl*76 + d4*4] =
          *(const f4*)&kpe[((size_t)(j0+jl)*H_ + h)*DK_ + d4*4];
    }
    __syncthreads();
    if (t < 128){
      float acc = 0.f;
#pragma unroll
      for (int d4=0; d4<16; d4++) acc += dot4(qv[d4], *(const f4*)&kl[t*76 + d4*4]);
      int j = j0 + t;
      bd[(size_t)(b*H_ + h)*S_ + j] = (acc + kpb[j*H_ + h]) * SCALE_;
    }
  }
}

// ---------------- pass1: scores[b][h][j] = SCALE*ac = key[j,b,:].wq_eff[b,h,:] ----------------
__global__ __launch_bounds__(256) void k_pass1(const float* __restrict__ key,
                                               const float* __restrict__ wq,
                                               float* __restrict__ scores){
  int b = blockIdx.x >> 5, jc = blockIdx.x & 31;
  __shared__ float wl[16*1028];   // padded stride to spread LDS banks
  __shared__ float sl[128*17];
  int t = threadIdx.x;
  for (int i=t; i<4096; i+=256){           // 4096 float4 = 16K floats
    int h = i >> 8, m4 = i & 255;
    *(f4*)&wl[h*1028 + m4*4] = *(const f4*)&wq[(size_t)b*H_*D_ + i*4];
  }
  __syncthreads();
  int lane = t & 63, w = t >> 6;
  int h = lane >> 2, s = lane & 3;
  for (int batch=0; batch<4; batch++){
    int jl0 = w*32 + batch*8;
    int j0 = jc*128 + jl0;
    const float* rp[8];
#pragma unroll
    for (int r=0;r<8;r++) rp[r] = key + ((size_t)(j0+r)*B_ + b)*D_ + s*4;
    float acc[8];
#pragma unroll
    for (int r=0;r<8;r++) acc[r] = 0.f;
#pragma unroll 4
    for (int c=0;c<64;c++){
      f4 wq4 = *(const f4*)&wl[h*1028 + c*16 + s*4];
#pragma unroll
      for (int r=0;r<8;r++){
        f4 kv = *(const f4*)(rp[r] + c*16);
        acc[r] += dot4(kv, wq4);
      }
    }
#pragma unroll
    for (int r=0;r<8;r++){
      float v = acc[r];
      v += __shfl_xor(v, 1);
      v += __shfl_xor(v, 2);
      if (s == 0) sl[(jl0 + r)*17 + h] = v;
    }
  }
  __syncthreads();
  for (int idx=t; idx<2048; idx+=256){
    int hh = idx >> 7, jl = idx & 127;
    scores[(size_t)(b*H_ + hh)*S_ + jc*128 + jl] = sl[jl*17 + hh];
  }
}

// ---------------- softmax over j per (b,h) ----------------
__global__ __launch_bounds__(256) void k_softmax(const float* __restrict__ scores,
                                                 const float* __restrict__ bd,
                                                 float* __restrict__ attn){
  int bh = blockIdx.x;
  int t = threadIdx.x;
  __shared__ float red[8];
  float sv[16];
  float mx = -1e30f;
#pragma unroll
  for (int i=0;i<16;i++){
    float v = scores[(size_t)bh*S_ + i*256 + t] + bd[(size_t)bh*S_ + i*256 + t];
    sv[i] = v; mx = fmaxf(mx, v);
  }
  for (int o=32;o>0;o>>=1) mx = fmaxf(mx, __shfl_xor(mx, o));
  if ((t & 63) == 0) red[t>>6] = mx;
  __syncthreads();
  mx = fmaxf(fmaxf(red[0],red[1]), fmaxf(red[2],red[3]));
  float sum = 0.f;
#pragma unroll
  for (int i=0;i<16;i++){ float e = __expf(sv[i]-mx); sv[i]=e; sum+=e; }
  for (int o=32;o>0;o>>=1) sum += __shfl_xor(sum, o);
  __syncthreads();
  if ((t & 63) == 0) red[4 + (t>>6)] = sum;
  __syncthreads();
  float inv = 1.f/(red[4]+red[5]+red[6]+red[7]);
#pragma unroll
  for (int i=0;i<16;i++) attn[(size_t)bh*S_ + i*256 + t] = sv[i]*inv;
}

// ---------------- pass2: partial[jc][b][h][m] = sum_{j in chunk} attn[j,b,h]*value[j,b,m] ----------------
__global__ __launch_bounds__(256) void k_pass2(const float* __restrict__ value,
                                               const float* __restrict__ attn,
                                               float* __restrict__ partial,
                                               int nchunk){
  int b  = blockIdx.x / nchunk;
  int jc = blockIdx.x % nchunk;
  int jper = S_ / nchunk;
  __shared__ float at[128*20];
  int t = threadIdx.x;
  f4 acc[16];
#pragma unroll
  for (int h=0;h<16;h++) acc[h] = f4{0.f,0.f,0.f,0.f};
  for (int tile=0; tile<jper/128; tile++){
    int j0 = jc*jper + tile*128;
    __syncthreads();
    for (int idx=t; idx<2048; idx+=256){
      int h = idx >> 7, jl = idx & 127;
      at[jl*20 + h] = attn[(size_t)(b*H_ + h)*S_ + j0 + jl];
    }
    __syncthreads();
    const float* vp = value + ((size_t)j0*B_ + b)*D_ + t*4;
#pragma unroll 2
    for (int j=0;j<128;j++){
      f4 v4 = *(const f4*)(vp + (size_t)j*B_*D_);
      f4 a0 = *(const f4*)&at[j*20];
      f4 a1 = *(const f4*)&at[j*20+4];
      f4 a2 = *(const f4*)&at[j*20+8];
      f4 a3 = *(const f4*)&at[j*20+12];
      float av[16] = {a0.x,a0.y,a0.z,a0.w, a1.x,a1.y,a1.z,a1.w,
                      a2.x,a2.y,a2.z,a2.w, a3.x,a3.y,a3.z,a3.w};
#pragma unroll
      for (int h=0;h<16;h++){
        acc[h].x += av[h]*v4.x; acc[h].y += av[h]*v4.y;
        acc[h].z += av[h]*v4.z; acc[h].w += av[h]*v4.w;
      }
    }
  }
#pragma unroll
  for (int h=0;h<16;h++)
    *(f4*)&partial[(((size_t)jc*B_ + b)*H_ + h)*D_ + t*4] = acc[h];
}

// ---------------- reduce partials -> y; x[b][h*64+d] = y.Wv + bv ----------------
__global__ __launch_bounds__(256) void k_reduce_ep1(const float* __restrict__ partial,
                                                    const float* __restrict__ Wv,
                                                    const float* __restrict__ bv,
                                                    float* __restrict__ x,
                                                    int nchunk){
  int b = blockIdx.x >> 4, h = blockIdx.x & 15;
  __shared__ float y[D_];
  __shared__ float xr[4][64];
  int t = threadIdx.x;
  f4 a = {0.f,0.f,0.f,0.f};
  for (int c=0;c<nchunk;c++){
    f4 p = *(const f4*)&partial[(((size_t)c*B_ + b)*H_ + h)*D_ + t*4];
    a.x+=p.x; a.y+=p.y; a.z+=p.z; a.w+=p.w;
  }
  *(f4*)&y[t*4] = a;
  __syncthreads();
  int d = t & 63, mq = t >> 6;
  float xp = 0.f;
  for (int m=mq*256; m<(mq+1)*256; m++)
    xp += y[m] * Wv[(size_t)m*D_ + h*DK_ + d];
  xr[mq][d] = xp;
  __syncthreads();
  if (t < 64)
    x[b*D_ + h*DK_ + t] = xr[0][t]+xr[1][t]+xr[2][t]+xr[3][t] + bv[h*DK_ + t];
}

// ---------------- out = x @ Wo + bo  (atomic hd-split) ----------------
__global__ __launch_bounds__(256) void k_ep2(const float* __restrict__ x,
                                             const float* __restrict__ Wo,
                                             const float* __restrict__ bo,
                                             float* __restrict__ out){
  int n   = (blockIdx.x & 3)*256 + threadIdx.x;
  int hd0 = (blockIdx.x >> 2)*64;
  float acc[B_];
  float binit = (hd0 == 0) ? bo[n] : 0.f;
#pragma unroll
  for (int b=0;b<B_;b++) acc[b] = binit;
  for (int hd=hd0; hd<hd0+64; hd++){
    float w = Wo[(size_t)hd*D_ + n];
#pragma unroll
    for (int b=0;b<B_;b++) acc[b] += x[b*D_ + hd] * w;
  }
  for (int b=0;b<B_;b++) atomicAdd(&out[b*D_ + n], acc[b]);
}

extern "C" void kernel_launch(void* const* d_in, const int* in_sizes, int n_in,
                              void* d_out, int out_size, void* d_ws, size_t ws_size,
                              hipStream_t stream) {
  const float* query = (const float*)d_in[0];
  const float* key   = (const float*)d_in[1];
  const float* value = (const float*)d_in[2];
  const float* Wq    = (const float*)d_in[3];
  const float* Wk    = (const float*)d_in[4];
  const float* Wv    = (const float*)d_in[5];
  const float* bv    = (const float*)d_in[6];
  const float* Wo    = (const float*)d_in[7];
  const float* bo    = (const float*)d_in[8];
  const float* kpe   = (const float*)d_in[9];
  const float* kpb   = (const float*)d_in[10];
  const float* qpb   = (const float*)d_in[11];
  float* out = (float*)d_out;
  float* ws  = (float*)d_ws;

  float* q    = ws;                    // 16384
  float* qq   = q    + 16384;          // 16384
  float* wq   = qq   + 16384;          // 262144
  float* bd   = wq   + 262144;         // 1048576
  float* sc   = bd   + 1048576;        // 1048576
  float* attn = sc   + 1048576;        // 1048576
  float* x    = attn + 1048576;        // 16384
  float* part = x    + 16384;          // nc2 * 262144
  size_t base_floats = (size_t)(part - ws);

  int nc2 = 32;
  while (nc2 > 1 && (base_floats + (size_t)nc2*262144)*sizeof(float) > ws_size) nc2 >>= 1;

  hipMemsetAsync(q, 0, 16384*sizeof(float), stream);
  hipMemsetAsync(d_out, 0, 16384*sizeof(float), stream);

  k_qgemm     <<<256, 256, 0, stream>>>(query, Wq, q);
  k_qq        <<<64,  256, 0, stream>>>(q, qpb, qq);
  k_wqeff     <<<4096,256, 0, stream>>>(Wk, qq, wq);
  k_bd        <<<256, 256, 0, stream>>>(q, kpe, kpb, bd);
  k_pass1     <<<512, 256, 0, stream>>>(key, wq, sc);
  k_softmax   <<<256, 256, 0, stream>>>(sc, bd, attn);
  k_pass2     <<<16*nc2, 256, 0, stream>>>(value, attn, part, nc2);
  k_reduce_ep1<<<256, 256, 0, stream>>>(part, Wv, bv, x, nc2);
  k_ep2       <<<64,  256, 0, stream>>>(x, Wo, bo, out);
}